// Round 16
// baseline (102.322 us; speedup 1.0000x reference)
//
#include <hip/hip_runtime.h>

// NCC loss, fused z-sweep, v16 = R15 (packed f32, ZC=40, T14 prefetch,
// literal ring) + parity-lagged sliding y-filter:
//   yf by 128 threads (2 outs each: 9-tap window + 1 slide, tap0 kept live)
//   into yf[2][256]; owners consume yf(s-1) from opposite parity in the same
//   phase. 2 unconditional barriers/slice; race-freedom via next body's A/B.
// Grid 800 x 256, LDS ~22.4 KB.

typedef float v2f __attribute__((ext_vector_type(2)));
typedef float v4f __attribute__((ext_vector_type(4)));

#define TX 16
#define TY 16
#define ZC 40
#define PH 24          // TY+8
#define PW 24          // TX+8
#define XFP 16         // v4f row stride
#define NSTEP 48       // ZC+8
#define NN 160
#define NPLANE (160*160)

__global__ void ncc_zero_ws(float* ws) { ws[0] = 0.0f; }

__global__ __launch_bounds__(256)
void ncc_fused(const float* __restrict__ pred, const float* __restrict__ target,
               float* __restrict__ ws) {
  __shared__ v2f st[PH * PW];          // staged (t,p)          4.6 KB
  __shared__ v4f xf4[PH * XFP];        // x-filt (t,p,t2,p2)    6.1 KB
  __shared__ float xf1[PH * XFP];      // x-filt tp             1.5 KB
  __shared__ v4f yf4[2][TY * TX];      // xy-filt 4 moments     8.2 KB
  __shared__ float yf1[2][TY * TX];    // xy-filt tp            2.0 KB
  __shared__ float wsum[4];

  const int tid = threadIdx.x;
  const int tx = tid & 15;
  const int ty = tid >> 4;             // 0..15

  int b = blockIdx.x;
  const int xt = b % 10; b /= 10;
  const int yt = b % 10; b /= 10;
  const int zc = b % 4;  b /= 4;
  const int x0 = xt * TX, y0 = yt * TY, z0 = zc * ZC;
  const size_t bbase = (size_t)b * (size_t)NN * (size_t)NPLANE;

  // ---- hoisted z-invariant stage geometry (3 strided positions) ----
  int soff0, soff1, soff2;
  bool sv0, sv1, sv2;
  {
    const int yy = tid / PW, xx = tid - yy * PW;
    const int gy = y0 + yy - 4, gx = x0 + xx - 4;
    sv0 = ((unsigned)gy < NN) && ((unsigned)gx < NN);
    soff0 = gy * NN + gx;
  }
  {
    const int pos = tid + 256;
    const int yy = pos / PW, xx = pos - yy * PW;
    const int gy = y0 + yy - 4, gx = x0 + xx - 4;
    sv1 = ((unsigned)gy < NN) && ((unsigned)gx < NN);
    soff1 = gy * NN + gx;
  }
  {
    const int pos = tid + 512;
    const int yy = pos / PW, xx = pos - yy * PW;
    const int gy = y0 + yy - 4, gx = x0 + xx - 4;
    sv2 = (tid < 64) && ((unsigned)gy < NN) && ((unsigned)gx < NN);
    soff2 = gy * NN + gx;
  }

  float rt0, rp0, rt1, rp1, rt2, rp2;  // prefetch regs (named -> static)

#define PRELOAD(SS) do {                                                      \
    const int zi_ = z0 - 4 + (SS);                                            \
    if ((unsigned)zi_ < NN) {                                                 \
      const size_t zb_ = bbase + (size_t)zi_ * (size_t)NPLANE;                \
      rt0 = sv0 ? target[zb_ + soff0] : 0.0f;                                 \
      rp0 = sv0 ? pred[zb_ + soff0]   : 0.0f;                                 \
      rt1 = sv1 ? target[zb_ + soff1] : 0.0f;                                 \
      rp1 = sv1 ? pred[zb_ + soff1]   : 0.0f;                                 \
      rt2 = sv2 ? target[zb_ + soff2] : 0.0f;                                 \
      rp2 = sv2 ? pred[zb_ + soff2]   : 0.0f;                                 \
    }                                                                         \
  } while (0)

  // ---- 9-tap x-filter, packed: pk_add + pk_fma + fma per tap ----
#define XFOUT(YY, XX) do {                                                    \
    v2f m01 = {0.0f, 0.0f};                                                   \
    v2f m23 = {0.0f, 0.0f};                                                   \
    float s_tp = 0.0f;                                                        \
    _Pragma("unroll")                                                         \
    for (int dx = 0; dx < 9; ++dx) {                                          \
      const v2f v = st[(YY) * PW + (XX) + dx];                                \
      m01 += v;                                                               \
      m23 = __builtin_elementwise_fma(v, v, m23);                             \
      s_tp = fmaf(v.x, v.y, s_tp);                                            \
    }                                                                         \
    v4f o_; o_.x = m01.x; o_.y = m01.y; o_.z = m23.x; o_.w = m23.y;           \
    xf4[(YY) * XFP + (XX)] = o_;                                              \
    xf1[(YY) * XFP + (XX)] = s_tp;                                            \
  } while (0)

  v2f b01[9], b23[9];
  float b4[9];
  v2f run01 = {0.0f, 0.0f}, run23 = {0.0f, 0.0f};
  float run4 = 0.0f;
  #pragma unroll
  for (int j = 0; j < 9; ++j) {
    b01[j] = (v2f){0.0f, 0.0f}; b23[j] = (v2f){0.0f, 0.0f}; b4[j] = 0.0f;
  }
  float acc = 0.0f;
  const float inv_kvol = 1.0f / 729.0f;

  // ---- body: produce slice S=s0+PP, consume slice S-1 at literal CSLOT ----
#define ZBODY(PP, CSLOT) do {                                                 \
    const int s = s0 + (PP);                                                  \
    const bool zvS = (s < NSTEP) && ((unsigned)(z0 - 4 + s) < NN);            \
    if (zvS) {                                                                \
      v2f w_;                                                                 \
      w_.x = rt0; w_.y = rp0; st[tid] = w_;                                   \
      w_.x = rt1; w_.y = rp1; st[tid + 256] = w_;                             \
      if (tid < 64) { w_.x = rt2; w_.y = rp2; st[tid + 512] = w_; }           \
    }                                                                         \
    __syncthreads();   /* A: st visible (unconditional) */                    \
    if (zvS) {                                                                \
      for (int pos = tid; pos < PH * TX; pos += 256) {                        \
        const int yy = pos >> 4;                                              \
        const int xx = pos & 15;                                              \
        XFOUT(yy, xx);                                                        \
      }                                                                       \
    }                                                                         \
    __syncthreads();   /* B: xf visible; st reads done (unconditional) */     \
    if (s + 1 < NSTEP) { PRELOAD(s + 1); }                                    \
    if (zvS && tid < 128) {                                                   \
      /* sliding yf: rows r0, r0+1 of column col -> yf[s&1] */                \
      const int col = tid & 15;                                               \
      const int r0  = (tid >> 4) * 2;                                         \
      v4f* ya_ = yf4[s & 1];                                                  \
      float* yb_ = yf1[s & 1];                                                \
      v4f t0 = xf4[r0 * XFP + col];                                           \
      float t01 = xf1[r0 * XFP + col];                                        \
      v4f w = t0;                                                             \
      float w1 = t01;                                                         \
      _Pragma("unroll")                                                       \
      for (int k = 1; k < 9; ++k) {                                           \
        w += xf4[(r0 + k) * XFP + col];                                       \
        w1 += xf1[(r0 + k) * XFP + col];                                      \
      }                                                                       \
      ya_[r0 * TX + col] = w;                                                 \
      yb_[r0 * TX + col] = w1;                                                \
      w  += xf4[(r0 + 9) * XFP + col] - t0;                                   \
      w1 += xf1[(r0 + 9) * XFP + col] - t01;                                  \
      ya_[(r0 + 1) * TX + col] = w;                                           \
      yb_[(r0 + 1) * TX + col] = w1;                                          \
    }                                                                         \
    /* consume slice s-1 from opposite parity (body s's A/B since write) */   \
    {                                                                         \
      const int sm1 = s - 1;                                                  \
      if (sm1 >= 0 && sm1 < NSTEP) {                                          \
        const bool zvm1 = ((unsigned)(z0 - 4 + sm1) < NN);                    \
        v2f c01 = {0.0f, 0.0f}, c23 = {0.0f, 0.0f};                           \
        float c4 = 0.0f;                                                      \
        if (zvm1) {                                                           \
          const v4f a = yf4[(s & 1) ^ 1][ty * TX + tx];                       \
          c4 = yf1[(s & 1) ^ 1][ty * TX + tx];                                \
          c01.x = a.x; c01.y = a.y; c23.x = a.z; c23.y = a.w;                 \
        }                                                                     \
        run01 += c01 - b01[(CSLOT)]; b01[(CSLOT)] = c01;                      \
        run23 += c23 - b23[(CSLOT)]; b23[(CSLOT)] = c23;                      \
        run4  += c4  - b4[(CSLOT)];  b4[(CSLOT)]  = c4;                       \
        if (sm1 >= 8) {                                                       \
          const v2f avg = run01 * inv_kvol;                                   \
          const v2f var = __builtin_elementwise_fma(-avg, run01, run23);      \
          const float cross = fmaf(-avg.y, run01.x, run4);                    \
          acc += (cross * cross) / (var.x * var.y + 1e-5f);                   \
        }                                                                     \
      }                                                                       \
    }                                                                         \
  } while (0)

  // ---- prologue: issue loads for slice 0 ----
  PRELOAD(0);

  // produce S=0..44 in loop-of-9; CSLOT=(S-1)%9 = {8,0,1,...,7} by position
  for (int s0 = 0; s0 < 45; s0 += 9) {
    ZBODY(0, 8); ZBODY(1, 0); ZBODY(2, 1); ZBODY(3, 2); ZBODY(4, 3);
    ZBODY(5, 4); ZBODY(6, 5); ZBODY(7, 6); ZBODY(8, 7);
  }
  // tail: S=45..48 (S=48 is consume-only; produce guard s<NSTEP fails)
  {
    const int s0 = 45;
    ZBODY(0, 8); ZBODY(1, 0); ZBODY(2, 1); ZBODY(3, 2);
  }
#undef ZBODY
#undef XFOUT
#undef PRELOAD

  // ---- reduction: wave shuffle -> LDS -> one atomicAdd per block ----
  #pragma unroll
  for (int off = 32; off > 0; off >>= 1)
    acc += __shfl_down(acc, off, 64);
  if ((tid & 63) == 0) wsum[tid >> 6] = acc;
  __syncthreads();
  if (tid == 0) {
    float tot = wsum[0] + wsum[1] + wsum[2] + wsum[3];
    atomicAdd(ws, tot);
  }
}

__global__ void ncc_finalize(const float* __restrict__ ws, float* __restrict__ out) {
  out[0] = -ws[0] * (1.0f / 8192000.0f);
}

extern "C" void kernel_launch(void* const* d_in, const int* in_sizes, int n_in,
                              void* d_out, int out_size, void* d_ws, size_t ws_size,
                              hipStream_t stream) {
  const float* pred   = (const float*)d_in[0];
  const float* target = (const float*)d_in[1];
  float* out = (float*)d_out;
  float* ws  = (float*)d_ws;

  ncc_zero_ws<<<1, 1, 0, stream>>>(ws);
  // grid: 10 x-tiles * 10 y-tiles * 4 z-chunks * 2 batches = 800 blocks
  ncc_fused<<<800, 256, 0, stream>>>(pred, target, ws);
  ncc_finalize<<<1, 1, 0, stream>>>(ws, out);
}